// Round 11
// baseline (2396.670 us; speedup 1.0000x reference)
//
#include <hip/hip_runtime.h>
#include <hip/hip_bf16.h>
#include <math.h>

#define BB 64
#define TT 256
#define LCH 16
#define DC 50
#define CHN 100
#define DW 300
#define DF 20
#define HID 256
#define G4 1024
#define INDIM 420
#define KPAD 448
#define NTAG 52
#define TSTART 50
#define TSTOP 51

// ------------------- workspace layout (bytes) -------------------
static constexpr size_t OFF_POOL  = 0;                       // 6,553,600 (dead after concat)
static constexpr size_t OFF_WH16F = 0;                       // 917,504 f16 (after concat)
static constexpr size_t OFF_WH16B = 917504;                  // -> 1,835,008
static constexpr size_t OFF_XH    = 6553600;                 // 14,680,064 f16 -> 21,233,664
static constexpr size_t OFF_HF    = 0;                       // 16,777,216 (lstm output)
static constexpr size_t OFF_HB    = 16777216;                // -> 33,554,432
static constexpr size_t OFF_XSF   = 34078720;                // 67,108,864
static constexpr size_t OFF_XSB   = 101187584;               // -> 168,296,448
static constexpr size_t OFF_FEATS = 168296448;               // 3,407,872 -> 171,704,320
static constexpr size_t OFF_WPF   = 171704320;               // 512 KB fp16 packed W_hh fwd
static constexpr size_t OFF_WPB   = 172752896;               // 512 KB fp16 packed W_hh bwd
static constexpr size_t OFF_LOSSB = 173801472;               // 256

typedef _Float16 v2h __attribute__((ext_vector_type(2)));
typedef _Float16 f16x8 __attribute__((ext_vector_type(8)));
typedef float f32x4 __attribute__((ext_vector_type(4)));
typedef unsigned uvec4 __attribute__((ext_vector_type(4)));   // clang-native vector for nt loads
union UH2 { unsigned u; v2h h; };
__device__ __forceinline__ float fdot2u(unsigned a, unsigned b, float c) {
    UH2 x, y; x.u = a; y.u = b;
    return __builtin_amdgcn_fdot2(x.h, y.h, c, false);
}
__device__ __forceinline__ float dot8(uint4 w, uint4 h, float acc) {
    acc = fdot2u(w.x, h.x, acc);
    acc = fdot2u(w.y, h.y, acc);
    acc = fdot2u(w.z, h.z, acc);
    acc = fdot2u(w.w, h.w, acc);
    return acc;
}
__device__ __forceinline__ uint4 ntload4(const uint4* p) {
    uvec4 v = __builtin_nontemporal_load((const uvec4*)p);
    uint4 r; r.x = v.x; r.y = v.y; r.z = v.z; r.w = v.w;
    return r;
}
#define KEEPU4(v) asm volatile("" : "+v"((v).x), "+v"((v).y), "+v"((v).z), "+v"((v).w))

__device__ __forceinline__ float sigm(float x) { return 1.0f / (1.0f + expf(-x)); }

// ---- fused prep: pack W_hh (both dirs) + cvt w_ih (both dirs)
__device__ __forceinline__ void packh_one(const float* __restrict__ w,
                                          _Float16* __restrict__ wph, int e) {
    int r  = e & 7;
    int j  = (e >> 3) & 255;
    int k8 = (e >> 11) & 7;
    int g  = (e >> 14) & 3;
    int s  = (e >> 16) & 3;
    wph[e] = (_Float16)w[(g * 256 + j) * HID + (s * 64 + k8 * 8 + r)];
}
__device__ __forceinline__ void cvtw_one(const float* __restrict__ w,
                                         _Float16* __restrict__ wh, int e) {
    int row = e / KPAD, k = e % KPAD;
    wh[e] = (k < INDIM) ? (_Float16)w[row * INDIM + k] : (_Float16)0.f;
}
__global__ void k_prep(const float* __restrict__ whf, const float* __restrict__ whb,
                       const float* __restrict__ wihf, const float* __restrict__ wihb,
                       _Float16* __restrict__ wpf, _Float16* __restrict__ wpb,
                       _Float16* __restrict__ wh16f, _Float16* __restrict__ wh16b) {
    int e = blockIdx.x * 256 + threadIdx.x;          // grid 5632 blocks
    if (e < 262144)                packh_one(whf, wpf, e);
    else if (e < 524288)           packh_one(whb, wpb, e - 262144);
    else if (e < 524288 + 458752)  cvtw_one(wihf, wh16f, e - 524288);
    else if (e < 524288 + 917504)  cvtw_one(wihb, wh16b, e - 983040);
}

// ---- char CNN: 8 words/block (2 concurrent x 4 iterations); conv weights in LDS
__global__ __launch_bounds__(256) void k_charcnn(const int* __restrict__ bchar,
                                                 const float* __restrict__ cemb,
                                                 const float* __restrict__ cw,
                                                 const float* __restrict__ cb,
                                                 float* __restrict__ pooled) {
    __shared__ float cwsh[150][100];   // [d*3+q][c], 60 KB
    __shared__ float ET[2][DC][20];
    __shared__ int ids[2][LCH];
    int tid = threadIdx.x;
    int wbase = blockIdx.x * 8;
    for (int i = tid; i < 15000; i += 256) {
        int row = i / 100, c = i % 100;
        cwsh[row][c] = cw[c * 150 + row];
    }
    int half = tid >> 7, c = tid & 127;
    float bcv = (c < CHN) ? cb[c] : 0.f;
    for (int g = 0; g < 8; g += 2) {
        __syncthreads();
        if (tid < 32) ids[tid >> 4][tid & 15] = bchar[(wbase + g + (tid >> 4)) * LCH + (tid & 15)];
        __syncthreads();
        for (int s2 = tid; s2 < 2 * DC * 18; s2 += 256) {
            int w2 = s2 / 900, rem = s2 % 900;
            int d = rem / 18, l = rem % 18;
            float v = 0.f;
            if (l >= 1 && l <= 16) v = cemb[ids[w2][l - 1] * DC + d];
            ET[w2][d][l] = v;
        }
        __syncthreads();
        if (c < CHN) {
            float acc[16];
#pragma unroll
            for (int l = 0; l < 16; l++) acc[l] = 0.f;
            for (int d = 0; d < DC; d++) {
                float e[18];
                float4 t0 = *(const float4*)&ET[half][d][0];
                float4 t1 = *(const float4*)&ET[half][d][4];
                float4 t2 = *(const float4*)&ET[half][d][8];
                float4 t3 = *(const float4*)&ET[half][d][12];
                e[0]=t0.x; e[1]=t0.y; e[2]=t0.z; e[3]=t0.w;
                e[4]=t1.x; e[5]=t1.y; e[6]=t1.z; e[7]=t1.w;
                e[8]=t2.x; e[9]=t2.y; e[10]=t2.z; e[11]=t2.w;
                e[12]=t3.x; e[13]=t3.y; e[14]=t3.z; e[15]=t3.w;
                e[16]=ET[half][d][16]; e[17]=ET[half][d][17];
                float w0 = cwsh[d * 3 + 0][c];
                float w1 = cwsh[d * 3 + 1][c];
                float w2 = cwsh[d * 3 + 2][c];
#pragma unroll
                for (int l = 0; l < 16; l++)
                    acc[l] += w0 * e[l] + w1 * e[l + 1] + w2 * e[l + 2];
            }
            float m = acc[0];
#pragma unroll
            for (int l = 1; l < 16; l++) m = fmaxf(m, acc[l]);
            pooled[(wbase + g + half) * CHN + c] = m + bcv;
        }
    }
}

// ---- assemble xh[16384][448] f16 = [word_emb | char_feats | feat_emb | 0-pad]
__global__ __launch_bounds__(128) void k_concat(const int* __restrict__ word,
                                                const int* __restrict__ featsidx,
                                                const int* __restrict__ recover,
                                                const float* __restrict__ wemb,
                                                const float* __restrict__ femb,
                                                const float* __restrict__ pooled,
                                                _Float16* __restrict__ xh) {
    int w = blockIdx.x;
    int tid = threadIdx.x;
    int b = w >> 8;
    int wid = word[w];
    _Float16* xr = xh + (size_t)w * KPAD;
    for (int c = tid; c < DW; c += 128) xr[c] = (_Float16)wemb[(size_t)wid * DW + c];
    int rc = recover[w];
    if (tid < CHN) xr[DW + tid] = (_Float16)pooled[rc * CHN + tid];
    if (tid < DF)  xr[DW + CHN + tid] = (_Float16)femb[featsidx[b] * DF + tid];
    if (tid >= 100 && tid < 100 + (KPAD - INDIM)) xr[INDIM + (tid - 100)] = (_Float16)0.f;
}

// ---- fused f16 MFMA GEMM for BOTH directions
__global__ __launch_bounds__(256) void k_gemm16b(const _Float16* __restrict__ A,
                                                 const _Float16* __restrict__ Bf,
                                                 const _Float16* __restrict__ Bb,
                                                 const float* __restrict__ biasf,
                                                 const float* __restrict__ biasb,
                                                 float* __restrict__ Cf,
                                                 float* __restrict__ Cb) {
    int tid = threadIdx.x;
    int wv = tid >> 6, l = tid & 63;
    int lm = l & 15, lk = l >> 4;
    int n0 = blockIdx.x * 64, m0 = blockIdx.y * 64;
    const _Float16* ap  = A  + (size_t)(m0 + wv * 16 + lm) * KPAD + lk * 8;
    const _Float16* bf0 = Bf + (size_t)(n0 + 0 * 16 + lm) * KPAD + lk * 8;
    const _Float16* bf1 = Bf + (size_t)(n0 + 1 * 16 + lm) * KPAD + lk * 8;
    const _Float16* bf2 = Bf + (size_t)(n0 + 2 * 16 + lm) * KPAD + lk * 8;
    const _Float16* bf3 = Bf + (size_t)(n0 + 3 * 16 + lm) * KPAD + lk * 8;
    const _Float16* bb0 = Bb + (size_t)(n0 + 0 * 16 + lm) * KPAD + lk * 8;
    const _Float16* bb1 = Bb + (size_t)(n0 + 1 * 16 + lm) * KPAD + lk * 8;
    const _Float16* bb2 = Bb + (size_t)(n0 + 2 * 16 + lm) * KPAD + lk * 8;
    const _Float16* bb3 = Bb + (size_t)(n0 + 3 * 16 + lm) * KPAD + lk * 8;
    f32x4 z = {0.f, 0.f, 0.f, 0.f};
    f32x4 af0 = z, af1 = z, af2 = z, af3 = z;
    f32x4 ab0 = z, ab1 = z, ab2 = z, ab3 = z;
    for (int k0 = 0; k0 < KPAD; k0 += 32) {
        f16x8 a  = *(const f16x8*)(ap + k0);
        f16x8 u0 = *(const f16x8*)(bf0 + k0);
        f16x8 u1 = *(const f16x8*)(bf1 + k0);
        f16x8 u2 = *(const f16x8*)(bf2 + k0);
        f16x8 u3 = *(const f16x8*)(bf3 + k0);
        f16x8 v0 = *(const f16x8*)(bb0 + k0);
        f16x8 v1 = *(const f16x8*)(bb1 + k0);
        f16x8 v2 = *(const f16x8*)(bb2 + k0);
        f16x8 v3 = *(const f16x8*)(bb3 + k0);
        af0 = __builtin_amdgcn_mfma_f32_16x16x32_f16(a, u0, af0, 0, 0, 0);
        af1 = __builtin_amdgcn_mfma_f32_16x16x32_f16(a, u1, af1, 0, 0, 0);
        af2 = __builtin_amdgcn_mfma_f32_16x16x32_f16(a, u2, af2, 0, 0, 0);
        af3 = __builtin_amdgcn_mfma_f32_16x16x32_f16(a, u3, af3, 0, 0, 0);
        ab0 = __builtin_amdgcn_mfma_f32_16x16x32_f16(a, v0, ab0, 0, 0, 0);
        ab1 = __builtin_amdgcn_mfma_f32_16x16x32_f16(a, v1, ab1, 0, 0, 0);
        ab2 = __builtin_amdgcn_mfma_f32_16x16x32_f16(a, v2, ab2, 0, 0, 0);
        ab3 = __builtin_amdgcn_mfma_f32_16x16x32_f16(a, v3, ab3, 0, 0, 0);
    }
    int orow = m0 + wv * 16 + lk * 4;
    f32x4 afs[4] = {af0, af1, af2, af3};
    f32x4 abs_[4] = {ab0, ab1, ab2, ab3};
#pragma unroll
    for (int jn = 0; jn < 4; jn++) {
        int col = n0 + jn * 16 + lm;
        float bvf = biasf[col], bvb = biasb[col];
#pragma unroll
        for (int r = 0; r < 4; r++) {
            Cf[(size_t)(orow + r) * G4 + col] = afs[jn][r] + bvf;
            Cb[(size_t)(orow + r) * G4 + col] = abs_[jn][r] + bvb;
        }
    }
}

// ---- masked BiLSTM (r8 structure): o-gate in 128 KB LDS; g-gate pinned in
// 32 VGPRs; i,f streamed 256 KB/step via NONTEMPORAL loads (bypass L1 fill).
__global__ __launch_bounds__(1024, 4) void k_lstm(const float* __restrict__ xs_f,
                                               const float* __restrict__ xs_b,
                                               const _Float16* __restrict__ wh_f,
                                               const _Float16* __restrict__ wh_b,
                                               const int* __restrict__ wlen,
                                               float* __restrict__ h_f,
                                               float* __restrict__ h_b) {
    int b = blockIdx.x & 63, d = blockIdx.x >> 6;
    const float* xs = d ? xs_b : xs_f;
    const uint4* wp4 = (const uint4*)(d ? wh_b : wh_f);
    float* ho = d ? h_b : h_f;
    int len = wlen[b];
    __shared__ uint4 olds4[8192];                 // o-gate weights, 128 KB
    __shared__ _Float16 __align__(16) hh[256];    // f16 h state
    __shared__ float part[4][4][256];             // [s][gate][unit], 16 KB
    int tid = threadIdx.x;
    int j = tid & 255, s = tid >> 8;
    const uint4* pi = wp4 + (size_t)((s * 4 + 0) * 8) * 256 + j;   // i (streamed)
    const uint4* pf = wp4 + (size_t)((s * 4 + 1) * 8) * 256 + j;   // f (streamed)
    uint4 wg[8];                                   // g-gate resident (32 VGPRs)
    {
        const uint4* pg = wp4 + (size_t)((s * 4 + 2) * 8) * 256 + j;
        const uint4* po = wp4 + (size_t)((s * 4 + 3) * 8) * 256 + j;
#pragma unroll
        for (int k8 = 0; k8 < 8; k8++) {
            wg[k8] = pg[k8 * 256];
            olds4[k8 * 1024 + tid] = po[k8 * 256];
        }
    }
#pragma unroll
    for (int k8 = 0; k8 < 8; k8++) KEEPU4(wg[k8]);
    if (tid < 128) ((unsigned*)hh)[tid] = 0u;
    float c = 0.f;
    const uint4* hsh4 = (const uint4*)hh;
    __syncthreads();
    for (int ss = 0; ss < len; ++ss) {
        int t = d ? (len - 1 - ss) : ss;
        float xv0, xv1, xv2, xv3;
        if (tid < 256) {
            const float* xr = xs + (size_t)(b * TT + t) * G4;
            xv0 = xr[tid];
            xv1 = xr[256 + tid];
            xv2 = xr[512 + tid];
            xv3 = xr[768 + tid];
        }
        asm volatile("" : "+v"(pi), "+v"(pf));
        float a0 = 0.f, a1 = 0.f, a2 = 0.f, a3 = 0.f;
#pragma unroll
        for (int k8 = 0; k8 < 8; k8++) {
            uint4 h4 = hsh4[s * 8 + k8];                       // broadcast
            uint4 wi = ntload4(&pi[k8 * 256]);
            uint4 wf = ntload4(&pf[k8 * 256]);
            uint4 wo = olds4[k8 * 1024 + tid];
            a0 = dot8(wi, h4, a0);
            a1 = dot8(wf, h4, a1);
            a2 = dot8(wg[k8], h4, a2);
            a3 = dot8(wo, h4, a3);
        }
        part[s][0][j] = a0;
        part[s][1][j] = a1;
        part[s][2][j] = a2;
        part[s][3][j] = a3;
        __syncthreads();
        if (tid < 256) {
            float s0 = part[0][0][tid] + part[1][0][tid] + part[2][0][tid] + part[3][0][tid] + xv0;
            float s1 = part[0][1][tid] + part[1][1][tid] + part[2][1][tid] + part[3][1][tid] + xv1;
            float s2 = part[0][2][tid] + part[1][2][tid] + part[2][2][tid] + part[3][2][tid] + xv2;
            float s3 = part[0][3][tid] + part[1][3][tid] + part[2][3][tid] + part[3][3][tid] + xv3;
            float ig = sigm(s0), fg = sigm(s1), zg = tanhf(s2), og = sigm(s3);
            c = fg * c + ig * zg;
            float h = og * tanhf(c);
            hh[tid] = (_Float16)h;
            ho[(size_t)(b * TT + t) * HID + tid] = h;
        }
        __syncthreads();
    }
}

// ---- projection: proj_w LDS-resident (stride-513 pad), 64 words per block
__global__ __launch_bounds__(256) void k_proj(const float* __restrict__ hf,
                                              const float* __restrict__ hb,
                                              const float* __restrict__ pw,
                                              const float* __restrict__ pb,
                                              float* __restrict__ feats) {
    __shared__ float pwsh[NTAG][513];
    __shared__ float hsh[512];
    __shared__ float part2[4][NTAG];
    int tid = threadIdx.x;
    int w0 = blockIdx.x * 64;
    for (int i = tid; i < NTAG * 512; i += 256) pwsh[i >> 9][i & 511] = pw[i];
    __syncthreads();
    int q = tid >> 6, t = tid & 63;
    for (int wi = 0; wi < 64; wi++) {
        int w = w0 + wi;
        hsh[tid]       = hf[(size_t)w * HID + tid];
        hsh[256 + tid] = hb[(size_t)w * HID + tid];
        __syncthreads();
        if (t < NTAG) {
            float ssum = 0.f;
            int k0 = q * 128;
            for (int k = 0; k < 128; k++) ssum += pwsh[t][k0 + k] * hsh[k0 + k];
            part2[q][t] = ssum;
        }
        __syncthreads();
        if (tid < NTAG)
            feats[(size_t)w * NTAG + tid] =
                part2[0][tid] + part2[1][tid] + part2[2][tid] + part2[3][tid] + pb[tid];
        __syncthreads();
    }
}

// ---- CRF: 2 waves; wave0 = forward logsumexp (+parallel gold), wave1 = viterbi.
// Inner 52-reductions split into 4 accumulator chains (latency).
__global__ __launch_bounds__(128) void k_crf(const float* __restrict__ feats,
                                             const float* __restrict__ trans,
                                             const int* __restrict__ wlen,
                                             const int* __restrict__ blabel,
                                             float* __restrict__ lossb,
                                             float* __restrict__ outtags) {
    __shared__ float Tm[NTAG * NTAG];
    __shared__ float alpha[NTAG], valpha[NTAG], frow[NTAG], red[NTAG], red2[NTAG];
    __shared__ unsigned char bp[TT - 1][NTAG];
    int b = blockIdx.x;
    int tid = threadIdx.x;
    int j = tid & 63, wv = tid >> 6;
    for (int s = tid; s < NTAG * NTAG; s += 128) Tm[s] = trans[s];
    __syncthreads();
    int len = wlen[b];
    const float* fb = feats + (size_t)b * TT * NTAG;
    if (tid < NTAG) {
        float a = fb[tid] + Tm[TSTART * NTAG + tid];
        alpha[tid] = a;
        valpha[tid] = a;
    }
    __syncthreads();
    for (int t = 1; t < len; t++) {
        if (tid < NTAG) frow[tid] = fb[(size_t)t * NTAG + tid];
        __syncthreads();
        float anew = 0.f, vnew = 0.f;
        int arg = 0;
        if (wv == 0 && j < NTAG) {
            float ma = -1e30f, mb = -1e30f, mc = -1e30f, md = -1e30f;
            for (int i = 0; i < 13; i++) {
                ma = fmaxf(ma, alpha[i]      + Tm[i * NTAG + j]);
                mb = fmaxf(mb, alpha[i + 13] + Tm[(i + 13) * NTAG + j]);
                mc = fmaxf(mc, alpha[i + 26] + Tm[(i + 26) * NTAG + j]);
                md = fmaxf(md, alpha[i + 39] + Tm[(i + 39) * NTAG + j]);
            }
            float m1 = fmaxf(fmaxf(ma, mb), fmaxf(mc, md));
            float sa = 0.f, sb = 0.f, sc = 0.f, sd = 0.f;
            for (int i = 0; i < 13; i++) {
                sa += expf(alpha[i]      + Tm[i * NTAG + j] - m1);
                sb += expf(alpha[i + 13] + Tm[(i + 13) * NTAG + j] - m1);
                sc += expf(alpha[i + 26] + Tm[(i + 26) * NTAG + j] - m1);
                sd += expf(alpha[i + 39] + Tm[(i + 39) * NTAG + j] - m1);
            }
            anew = m1 + logf((sa + sb) + (sc + sd)) + frow[j];
        } else if (wv == 1 && j < NTAG) {
            float va = -1e30f, vb = -1e30f, vc = -1e30f, vd = -1e30f;
            int ia = 0, ib = 13, ic = 26, id2 = 39;
            for (int i = 0; i < 13; i++) {
                float s0 = valpha[i]      + Tm[i * NTAG + j];        if (s0 > va) { va = s0; ia = i; }
                float s1 = valpha[i + 13] + Tm[(i + 13) * NTAG + j]; if (s1 > vb) { vb = s1; ib = i + 13; }
                float s2 = valpha[i + 26] + Tm[(i + 26) * NTAG + j]; if (s2 > vc) { vc = s2; ic = i + 26; }
                float s3 = valpha[i + 39] + Tm[(i + 39) * NTAG + j]; if (s3 > vd) { vd = s3; id2 = i + 39; }
            }
            float vm = va; arg = ia;
            if (vb > vm) { vm = vb; arg = ib; }
            if (vc > vm) { vm = vc; arg = ic; }
            if (vd > vm) { vm = vd; arg = id2; }
            vnew = vm + frow[j];
        }
        __syncthreads();
        if (wv == 0 && j < NTAG) {
            alpha[j] = anew;
        } else if (wv == 1 && j < NTAG) {
            valpha[j] = vnew;
            bp[t - 1][j] = (unsigned char)arg;
        }
        __syncthreads();
    }
    if (tid < NTAG) {
        red[tid]  = alpha[tid] + Tm[tid * NTAG + TSTOP];
        red2[tid] = valpha[tid] + Tm[tid * NTAG + TSTOP];
    }
    __syncthreads();
    // wave0: parallel gold transition+emission sum over t=1..len-1
    float gpart = 0.f;
    if (wv == 0) {
        const int* lab = blabel + b * TT;
        for (int t = 1 + j; t < len; t += 64)
            gpart += Tm[lab[t - 1] * NTAG + lab[t]] + fb[(size_t)t * NTAG + lab[t]];
#pragma unroll
        for (int m = 32; m; m >>= 1) gpart += __shfl_xor(gpart, m);
    }
    if (tid == 0) {
        float m1 = red[0];
        for (int i = 1; i < NTAG; i++) m1 = fmaxf(m1, red[i]);
        float ssum = 0.f;
        for (int i = 0; i < NTAG; i++) ssum += expf(red[i] - m1);
        float Zg = m1 + logf(ssum);
        const int* lab = blabel + b * TT;
        float goldv = Tm[TSTART * NTAG + lab[0]] + fb[lab[0]] + gpart
                    + Tm[lab[len - 1] * NTAG + TSTOP];
        lossb[b] = Zg - goldv;
    } else if (tid == 64) {
        int best = 0;
        float vm = red2[0];
        for (int i = 1; i < NTAG; i++)
            if (red2[i] > vm) { vm = red2[i]; best = i; }
        float* ot = outtags + (size_t)b * TT;
        int tag = best;
        ot[len - 1] = (float)tag;
        for (int t = len - 2; t >= 0; t--) {
            tag = bp[t][tag];
            ot[t] = (float)tag;
        }
        for (int t = len; t < TT; t++) ot[t] = 0.f;
    }
}

// ---- deterministic final loss reduction
__global__ void k_loss(const float* __restrict__ lossb, float* __restrict__ out) {
    if (threadIdx.x == 0 && blockIdx.x == 0) {
        float s = 0.f;
        for (int i = 0; i < BB; i++) s += lossb[i];
        out[0] = s;
    }
}

extern "C" void kernel_launch(void* const* d_in, const int* in_sizes, int n_in,
                              void* d_out, int out_size, void* d_ws, size_t ws_size,
                              hipStream_t stream) {
    const int* batch_word     = (const int*)d_in[0];
    const int* batch_features = (const int*)d_in[1];
    const int* batch_wordlen  = (const int*)d_in[2];
    const int* batch_char     = (const int*)d_in[3];
    const int* batch_recover  = (const int*)d_in[5];
    const int* batch_label    = (const int*)d_in[7];
    const float* char_emb = (const float*)d_in[8];
    const float* conv_w   = (const float*)d_in[9];
    const float* conv_b   = (const float*)d_in[10];
    const float* word_emb = (const float*)d_in[11];
    const float* feat_emb = (const float*)d_in[12];
    const float* w_ih_f   = (const float*)d_in[13];
    const float* w_hh_f   = (const float*)d_in[14];
    const float* b_f      = (const float*)d_in[15];
    const float* w_ih_b   = (const float*)d_in[16];
    const float* w_hh_b   = (const float*)d_in[17];
    const float* b_b      = (const float*)d_in[18];
    const float* proj_w   = (const float*)d_in[19];
    const float* proj_b   = (const float*)d_in[20];
    const float* trans    = (const float*)d_in[21];

    char* ws = (char*)d_ws;
    float* pooled   = (float*)(ws + OFF_POOL);
    _Float16* wh16f = (_Float16*)(ws + OFF_WH16F);
    _Float16* wh16b = (_Float16*)(ws + OFF_WH16B);
    _Float16* xh    = (_Float16*)(ws + OFF_XH);
    float* h_f    = (float*)(ws + OFF_HF);
    float* h_b    = (float*)(ws + OFF_HB);
    float* xs_f   = (float*)(ws + OFF_XSF);
    float* xs_b   = (float*)(ws + OFF_XSB);
    float* feats  = (float*)(ws + OFF_FEATS);
    _Float16* wh_f = (_Float16*)(ws + OFF_WPF);
    _Float16* wh_b = (_Float16*)(ws + OFF_WPB);
    float* lossb  = (float*)(ws + OFF_LOSSB);

    k_charcnn<<<(BB * TT) / 8, 256, 0, stream>>>(batch_char, char_emb, conv_w, conv_b, pooled);
    k_concat<<<BB * TT, 128, 0, stream>>>(batch_word, batch_features, batch_recover,
                                          word_emb, feat_emb, pooled, xh);
    // pooled dead now -> wh16 conversions may overwrite that region; W_hh packs
    // write to their own region. One fused prep dispatch.
    k_prep<<<5632, 256, 0, stream>>>(w_hh_f, w_hh_b, w_ih_f, w_ih_b,
                                     wh_f, wh_b, wh16f, wh16b);
    k_gemm16b<<<dim3(G4 / 64, (BB * TT) / 64), 256, 0, stream>>>(xh, wh16f, wh16b,
                                                                 b_f, b_b, xs_f, xs_b);
    k_lstm<<<128, 1024, 0, stream>>>(xs_f, xs_b, wh_f, wh_b, batch_wordlen, h_f, h_b);
    k_proj<<<(BB * TT) / 64, 256, 0, stream>>>(h_f, h_b, proj_w, proj_b, feats);
    k_crf<<<BB, 128, 0, stream>>>(feats, trans, batch_wordlen, batch_label,
                                  lossb, (float*)d_out + 1);
    k_loss<<<1, 64, 0, stream>>>(lossb, (float*)d_out);
}

// Round 12
// 1901.444 us; speedup vs baseline: 1.2604x; 1.2604x over previous
//
#include <hip/hip_runtime.h>
#include <hip/hip_bf16.h>
#include <math.h>

#define BB 64
#define TT 256
#define LCH 16
#define DC 50
#define CHN 100
#define DW 300
#define DF 20
#define HID 256
#define G4 1024
#define INDIM 420
#define KPAD 448
#define NTAG 52
#define TSTART 50
#define TSTOP 51

// ------------------- workspace layout (bytes) -------------------
static constexpr size_t OFF_POOL  = 0;                       // 6,553,600 (dead after concat)
static constexpr size_t OFF_WH16F = 0;                       // 917,504 f16 (after concat)
static constexpr size_t OFF_WH16B = 917504;                  // -> 1,835,008
static constexpr size_t OFF_XH    = 6553600;                 // 14,680,064 f16 -> 21,233,664
static constexpr size_t OFF_HF    = 0;                       // 16,777,216 (lstm output)
static constexpr size_t OFF_HB    = 16777216;                // -> 33,554,432
static constexpr size_t OFF_XSF   = 34078720;                // 67,108,864
static constexpr size_t OFF_XSB   = 101187584;               // -> 168,296,448
static constexpr size_t OFF_FEATS = 168296448;               // 3,407,872 -> 171,704,320
static constexpr size_t OFF_WPF   = 171704320;               // 512 KB fp16 packed W_hh fwd
static constexpr size_t OFF_WPB   = 172752896;               // 512 KB fp16 packed W_hh bwd
static constexpr size_t OFF_LOSSB = 173801472;               // 256

typedef _Float16 v2h __attribute__((ext_vector_type(2)));
typedef _Float16 f16x8 __attribute__((ext_vector_type(8)));
typedef float f32x4 __attribute__((ext_vector_type(4)));
union UH2 { unsigned u; v2h h; };
__device__ __forceinline__ float fdot2u(unsigned a, unsigned b, float c) {
    UH2 x, y; x.u = a; y.u = b;
    return __builtin_amdgcn_fdot2(x.h, y.h, c, false);
}
__device__ __forceinline__ float dot8(uint4 w, uint4 h, float acc) {
    acc = fdot2u(w.x, h.x, acc);
    acc = fdot2u(w.y, h.y, acc);
    acc = fdot2u(w.z, h.z, acc);
    acc = fdot2u(w.w, h.w, acc);
    return acc;
}
#define KEEPU4(v) asm volatile("" : "+v"((v).x), "+v"((v).y), "+v"((v).z), "+v"((v).w))

__device__ __forceinline__ float sigm(float x) { return 1.0f / (1.0f + expf(-x)); }

// ---- fused prep: pack W_hh (both dirs) + cvt w_ih (both dirs)
__device__ __forceinline__ void packh_one(const float* __restrict__ w,
                                          _Float16* __restrict__ wph, int e) {
    int r  = e & 7;
    int j  = (e >> 3) & 255;
    int k8 = (e >> 11) & 7;
    int g  = (e >> 14) & 3;
    int s  = (e >> 16) & 3;
    wph[e] = (_Float16)w[(g * 256 + j) * HID + (s * 64 + k8 * 8 + r)];
}
__device__ __forceinline__ void cvtw_one(const float* __restrict__ w,
                                         _Float16* __restrict__ wh, int e) {
    int row = e / KPAD, k = e % KPAD;
    wh[e] = (k < INDIM) ? (_Float16)w[row * INDIM + k] : (_Float16)0.f;
}
__global__ void k_prep(const float* __restrict__ whf, const float* __restrict__ whb,
                       const float* __restrict__ wihf, const float* __restrict__ wihb,
                       _Float16* __restrict__ wpf, _Float16* __restrict__ wpb,
                       _Float16* __restrict__ wh16f, _Float16* __restrict__ wh16b) {
    int e = blockIdx.x * 256 + threadIdx.x;          // grid 5632 blocks
    if (e < 262144)                packh_one(whf, wpf, e);
    else if (e < 524288)           packh_one(whb, wpb, e - 262144);
    else if (e < 524288 + 458752)  cvtw_one(wihf, wh16f, e - 524288);
    else if (e < 524288 + 917504)  cvtw_one(wihb, wh16b, e - 983040);
}

// ---- char CNN: 8 words/block (2 concurrent x 4 iterations); conv weights in LDS
__global__ __launch_bounds__(256) void k_charcnn(const int* __restrict__ bchar,
                                                 const float* __restrict__ cemb,
                                                 const float* __restrict__ cw,
                                                 const float* __restrict__ cb,
                                                 float* __restrict__ pooled) {
    __shared__ float cwsh[150][100];   // [d*3+q][c], 60 KB
    __shared__ float ET[2][DC][20];
    __shared__ int ids[2][LCH];
    int tid = threadIdx.x;
    int wbase = blockIdx.x * 8;
    for (int i = tid; i < 15000; i += 256) {
        int row = i / 100, c = i % 100;
        cwsh[row][c] = cw[c * 150 + row];
    }
    int half = tid >> 7, c = tid & 127;
    float bcv = (c < CHN) ? cb[c] : 0.f;
    for (int g = 0; g < 8; g += 2) {
        __syncthreads();
        if (tid < 32) ids[tid >> 4][tid & 15] = bchar[(wbase + g + (tid >> 4)) * LCH + (tid & 15)];
        __syncthreads();
        for (int s2 = tid; s2 < 2 * DC * 18; s2 += 256) {
            int w2 = s2 / 900, rem = s2 % 900;
            int d = rem / 18, l = rem % 18;
            float v = 0.f;
            if (l >= 1 && l <= 16) v = cemb[ids[w2][l - 1] * DC + d];
            ET[w2][d][l] = v;
        }
        __syncthreads();
        if (c < CHN) {
            float acc[16];
#pragma unroll
            for (int l = 0; l < 16; l++) acc[l] = 0.f;
            for (int d = 0; d < DC; d++) {
                float e[18];
                float4 t0 = *(const float4*)&ET[half][d][0];
                float4 t1 = *(const float4*)&ET[half][d][4];
                float4 t2 = *(const float4*)&ET[half][d][8];
                float4 t3 = *(const float4*)&ET[half][d][12];
                e[0]=t0.x; e[1]=t0.y; e[2]=t0.z; e[3]=t0.w;
                e[4]=t1.x; e[5]=t1.y; e[6]=t1.z; e[7]=t1.w;
                e[8]=t2.x; e[9]=t2.y; e[10]=t2.z; e[11]=t2.w;
                e[12]=t3.x; e[13]=t3.y; e[14]=t3.z; e[15]=t3.w;
                e[16]=ET[half][d][16]; e[17]=ET[half][d][17];
                float w0 = cwsh[d * 3 + 0][c];
                float w1 = cwsh[d * 3 + 1][c];
                float w2 = cwsh[d * 3 + 2][c];
#pragma unroll
                for (int l = 0; l < 16; l++)
                    acc[l] += w0 * e[l] + w1 * e[l + 1] + w2 * e[l + 2];
            }
            float m = acc[0];
#pragma unroll
            for (int l = 1; l < 16; l++) m = fmaxf(m, acc[l]);
            pooled[(wbase + g + half) * CHN + c] = m + bcv;
        }
    }
}

// ---- assemble xh[16384][448] f16; 8 words per block (2048 blocks)
__global__ __launch_bounds__(128) void k_concat(const int* __restrict__ word,
                                                const int* __restrict__ featsidx,
                                                const int* __restrict__ recover,
                                                const float* __restrict__ wemb,
                                                const float* __restrict__ femb,
                                                const float* __restrict__ pooled,
                                                _Float16* __restrict__ xh) {
    int tid = threadIdx.x;
    for (int wi = 0; wi < 8; wi++) {
        int w = blockIdx.x * 8 + wi;
        int b = w >> 8;
        int wid = word[w];
        _Float16* xr = xh + (size_t)w * KPAD;
        for (int c = tid; c < DW; c += 128) xr[c] = (_Float16)wemb[(size_t)wid * DW + c];
        int rc = recover[w];
        if (tid < CHN) xr[DW + tid] = (_Float16)pooled[rc * CHN + tid];
        if (tid < DF)  xr[DW + CHN + tid] = (_Float16)femb[featsidx[b] * DF + tid];
        if (tid >= 100 && tid < 100 + (KPAD - INDIM)) xr[INDIM + (tid - 100)] = (_Float16)0.f;
    }
}

// ---- fused f16 MFMA GEMM for BOTH directions
__global__ __launch_bounds__(256) void k_gemm16b(const _Float16* __restrict__ A,
                                                 const _Float16* __restrict__ Bf,
                                                 const _Float16* __restrict__ Bb,
                                                 const float* __restrict__ biasf,
                                                 const float* __restrict__ biasb,
                                                 float* __restrict__ Cf,
                                                 float* __restrict__ Cb) {
    int tid = threadIdx.x;
    int wv = tid >> 6, l = tid & 63;
    int lm = l & 15, lk = l >> 4;
    int n0 = blockIdx.x * 64, m0 = blockIdx.y * 64;
    const _Float16* ap  = A  + (size_t)(m0 + wv * 16 + lm) * KPAD + lk * 8;
    const _Float16* bf0 = Bf + (size_t)(n0 + 0 * 16 + lm) * KPAD + lk * 8;
    const _Float16* bf1 = Bf + (size_t)(n0 + 1 * 16 + lm) * KPAD + lk * 8;
    const _Float16* bf2 = Bf + (size_t)(n0 + 2 * 16 + lm) * KPAD + lk * 8;
    const _Float16* bf3 = Bf + (size_t)(n0 + 3 * 16 + lm) * KPAD + lk * 8;
    const _Float16* bb0 = Bb + (size_t)(n0 + 0 * 16 + lm) * KPAD + lk * 8;
    const _Float16* bb1 = Bb + (size_t)(n0 + 1 * 16 + lm) * KPAD + lk * 8;
    const _Float16* bb2 = Bb + (size_t)(n0 + 2 * 16 + lm) * KPAD + lk * 8;
    const _Float16* bb3 = Bb + (size_t)(n0 + 3 * 16 + lm) * KPAD + lk * 8;
    f32x4 z = {0.f, 0.f, 0.f, 0.f};
    f32x4 af0 = z, af1 = z, af2 = z, af3 = z;
    f32x4 ab0 = z, ab1 = z, ab2 = z, ab3 = z;
    for (int k0 = 0; k0 < KPAD; k0 += 32) {
        f16x8 a  = *(const f16x8*)(ap + k0);
        f16x8 u0 = *(const f16x8*)(bf0 + k0);
        f16x8 u1 = *(const f16x8*)(bf1 + k0);
        f16x8 u2 = *(const f16x8*)(bf2 + k0);
        f16x8 u3 = *(const f16x8*)(bf3 + k0);
        f16x8 v0 = *(const f16x8*)(bb0 + k0);
        f16x8 v1 = *(const f16x8*)(bb1 + k0);
        f16x8 v2 = *(const f16x8*)(bb2 + k0);
        f16x8 v3 = *(const f16x8*)(bb3 + k0);
        af0 = __builtin_amdgcn_mfma_f32_16x16x32_f16(a, u0, af0, 0, 0, 0);
        af1 = __builtin_amdgcn_mfma_f32_16x16x32_f16(a, u1, af1, 0, 0, 0);
        af2 = __builtin_amdgcn_mfma_f32_16x16x32_f16(a, u2, af2, 0, 0, 0);
        af3 = __builtin_amdgcn_mfma_f32_16x16x32_f16(a, u3, af3, 0, 0, 0);
        ab0 = __builtin_amdgcn_mfma_f32_16x16x32_f16(a, v0, ab0, 0, 0, 0);
        ab1 = __builtin_amdgcn_mfma_f32_16x16x32_f16(a, v1, ab1, 0, 0, 0);
        ab2 = __builtin_amdgcn_mfma_f32_16x16x32_f16(a, v2, ab2, 0, 0, 0);
        ab3 = __builtin_amdgcn_mfma_f32_16x16x32_f16(a, v3, ab3, 0, 0, 0);
    }
    int orow = m0 + wv * 16 + lk * 4;
    f32x4 afs[4] = {af0, af1, af2, af3};
    f32x4 abs_[4] = {ab0, ab1, ab2, ab3};
#pragma unroll
    for (int jn = 0; jn < 4; jn++) {
        int col = n0 + jn * 16 + lm;
        float bvf = biasf[col], bvb = biasb[col];
#pragma unroll
        for (int r = 0; r < 4; r++) {
            Cf[(size_t)(orow + r) * G4 + col] = afs[jn][r] + bvf;
            Cb[(size_t)(orow + r) * G4 + col] = abs_[jn][r] + bvb;
        }
    }
}

// ---- masked BiLSTM (r8 structure, PLAIN loads): o-gate in 128 KB LDS;
// g-gate pinned in 32 VGPRs; i,f streamed 256 KB/step from L2 (cached —
// nt-loads evicted the shared weight set from L2 and cost +47%, reverted).
__global__ __launch_bounds__(1024, 4) void k_lstm(const float* __restrict__ xs_f,
                                               const float* __restrict__ xs_b,
                                               const _Float16* __restrict__ wh_f,
                                               const _Float16* __restrict__ wh_b,
                                               const int* __restrict__ wlen,
                                               float* __restrict__ h_f,
                                               float* __restrict__ h_b) {
    int b = blockIdx.x & 63, d = blockIdx.x >> 6;
    const float* xs = d ? xs_b : xs_f;
    const uint4* wp4 = (const uint4*)(d ? wh_b : wh_f);
    float* ho = d ? h_b : h_f;
    int len = wlen[b];
    __shared__ uint4 olds4[8192];                 // o-gate weights, 128 KB
    __shared__ _Float16 __align__(16) hh[256];    // f16 h state
    __shared__ float part[4][4][256];             // [s][gate][unit], 16 KB
    int tid = threadIdx.x;
    int j = tid & 255, s = tid >> 8;
    const uint4* pi = wp4 + (size_t)((s * 4 + 0) * 8) * 256 + j;   // i (streamed)
    const uint4* pf = wp4 + (size_t)((s * 4 + 1) * 8) * 256 + j;   // f (streamed)
    uint4 wg[8];                                   // g-gate resident (32 VGPRs)
    {
        const uint4* pg = wp4 + (size_t)((s * 4 + 2) * 8) * 256 + j;
        const uint4* po = wp4 + (size_t)((s * 4 + 3) * 8) * 256 + j;
#pragma unroll
        for (int k8 = 0; k8 < 8; k8++) {
            wg[k8] = pg[k8 * 256];
            olds4[k8 * 1024 + tid] = po[k8 * 256];
        }
    }
#pragma unroll
    for (int k8 = 0; k8 < 8; k8++) KEEPU4(wg[k8]);
    if (tid < 128) ((unsigned*)hh)[tid] = 0u;
    float c = 0.f;
    const uint4* hsh4 = (const uint4*)hh;
    __syncthreads();
    for (int ss = 0; ss < len; ++ss) {
        int t = d ? (len - 1 - ss) : ss;
        float xv0, xv1, xv2, xv3;
        if (tid < 256) {
            const float* xr = xs + (size_t)(b * TT + t) * G4;
            xv0 = xr[tid];
            xv1 = xr[256 + tid];
            xv2 = xr[512 + tid];
            xv3 = xr[768 + tid];
        }
        asm volatile("" : "+v"(pi), "+v"(pf));
        float a0 = 0.f, a1 = 0.f, a2 = 0.f, a3 = 0.f;
#pragma unroll
        for (int k8 = 0; k8 < 8; k8++) {
            uint4 h4 = hsh4[s * 8 + k8];                       // broadcast
            uint4 wi = pi[k8 * 256];
            uint4 wf = pf[k8 * 256];
            uint4 wo = olds4[k8 * 1024 + tid];
            a0 = dot8(wi, h4, a0);
            a1 = dot8(wf, h4, a1);
            a2 = dot8(wg[k8], h4, a2);
            a3 = dot8(wo, h4, a3);
        }
        part[s][0][j] = a0;
        part[s][1][j] = a1;
        part[s][2][j] = a2;
        part[s][3][j] = a3;
        __syncthreads();
        if (tid < 256) {
            float s0 = part[0][0][tid] + part[1][0][tid] + part[2][0][tid] + part[3][0][tid] + xv0;
            float s1 = part[0][1][tid] + part[1][1][tid] + part[2][1][tid] + part[3][1][tid] + xv1;
            float s2 = part[0][2][tid] + part[1][2][tid] + part[2][2][tid] + part[3][2][tid] + xv2;
            float s3 = part[0][3][tid] + part[1][3][tid] + part[2][3][tid] + part[3][3][tid] + xv3;
            float ig = sigm(s0), fg = sigm(s1), zg = tanhf(s2), og = sigm(s3);
            c = fg * c + ig * zg;
            float h = og * tanhf(c);
            hh[tid] = (_Float16)h;
            ho[(size_t)(b * TT + t) * HID + tid] = h;
        }
        __syncthreads();
    }
}

// ---- projection: proj_w LDS-resident (stride-513 pad), 64 words per block
__global__ __launch_bounds__(256) void k_proj(const float* __restrict__ hf,
                                              const float* __restrict__ hb,
                                              const float* __restrict__ pw,
                                              const float* __restrict__ pb,
                                              float* __restrict__ feats) {
    __shared__ float pwsh[NTAG][513];
    __shared__ float hsh[512];
    __shared__ float part2[4][NTAG];
    int tid = threadIdx.x;
    int w0 = blockIdx.x * 64;
    for (int i = tid; i < NTAG * 512; i += 256) pwsh[i >> 9][i & 511] = pw[i];
    __syncthreads();
    int q = tid >> 6, t = tid & 63;
    for (int wi = 0; wi < 64; wi++) {
        int w = w0 + wi;
        hsh[tid]       = hf[(size_t)w * HID + tid];
        hsh[256 + tid] = hb[(size_t)w * HID + tid];
        __syncthreads();
        if (t < NTAG) {
            float ssum = 0.f;
            int k0 = q * 128;
            for (int k = 0; k < 128; k++) ssum += pwsh[t][k0 + k] * hsh[k0 + k];
            part2[q][t] = ssum;
        }
        __syncthreads();
        if (tid < NTAG)
            feats[(size_t)w * NTAG + tid] =
                part2[0][tid] + part2[1][tid] + part2[2][tid] + part2[3][tid] + pb[tid];
        __syncthreads();
    }
}

// ---- CRF: 2 waves; wave0 = forward logsumexp (+parallel gold), wave1 = viterbi.
__global__ __launch_bounds__(128) void k_crf(const float* __restrict__ feats,
                                             const float* __restrict__ trans,
                                             const int* __restrict__ wlen,
                                             const int* __restrict__ blabel,
                                             float* __restrict__ lossb,
                                             float* __restrict__ outtags) {
    __shared__ float Tm[NTAG * NTAG];
    __shared__ float alpha[NTAG], valpha[NTAG], frow[NTAG], red[NTAG], red2[NTAG];
    __shared__ unsigned char bp[TT - 1][NTAG];
    int b = blockIdx.x;
    int tid = threadIdx.x;
    int j = tid & 63, wv = tid >> 6;
    for (int s = tid; s < NTAG * NTAG; s += 128) Tm[s] = trans[s];
    __syncthreads();
    int len = wlen[b];
    const float* fb = feats + (size_t)b * TT * NTAG;
    if (tid < NTAG) {
        float a = fb[tid] + Tm[TSTART * NTAG + tid];
        alpha[tid] = a;
        valpha[tid] = a;
    }
    __syncthreads();
    for (int t = 1; t < len; t++) {
        if (tid < NTAG) frow[tid] = fb[(size_t)t * NTAG + tid];
        __syncthreads();
        float anew = 0.f, vnew = 0.f;
        int arg = 0;
        if (wv == 0 && j < NTAG) {
            float ma = -1e30f, mb = -1e30f, mc = -1e30f, md = -1e30f;
            for (int i = 0; i < 13; i++) {
                ma = fmaxf(ma, alpha[i]      + Tm[i * NTAG + j]);
                mb = fmaxf(mb, alpha[i + 13] + Tm[(i + 13) * NTAG + j]);
                mc = fmaxf(mc, alpha[i + 26] + Tm[(i + 26) * NTAG + j]);
                md = fmaxf(md, alpha[i + 39] + Tm[(i + 39) * NTAG + j]);
            }
            float m1 = fmaxf(fmaxf(ma, mb), fmaxf(mc, md));
            float sa = 0.f, sb = 0.f, sc = 0.f, sd = 0.f;
            for (int i = 0; i < 13; i++) {
                sa += expf(alpha[i]      + Tm[i * NTAG + j] - m1);
                sb += expf(alpha[i + 13] + Tm[(i + 13) * NTAG + j] - m1);
                sc += expf(alpha[i + 26] + Tm[(i + 26) * NTAG + j] - m1);
                sd += expf(alpha[i + 39] + Tm[(i + 39) * NTAG + j] - m1);
            }
            anew = m1 + logf((sa + sb) + (sc + sd)) + frow[j];
        } else if (wv == 1 && j < NTAG) {
            float va = -1e30f, vb = -1e30f, vc = -1e30f, vd = -1e30f;
            int ia = 0, ib = 13, ic = 26, id2 = 39;
            for (int i = 0; i < 13; i++) {
                float s0 = valpha[i]      + Tm[i * NTAG + j];        if (s0 > va) { va = s0; ia = i; }
                float s1 = valpha[i + 13] + Tm[(i + 13) * NTAG + j]; if (s1 > vb) { vb = s1; ib = i + 13; }
                float s2 = valpha[i + 26] + Tm[(i + 26) * NTAG + j]; if (s2 > vc) { vc = s2; ic = i + 26; }
                float s3 = valpha[i + 39] + Tm[(i + 39) * NTAG + j]; if (s3 > vd) { vd = s3; id2 = i + 39; }
            }
            float vm = va; arg = ia;
            if (vb > vm) { vm = vb; arg = ib; }
            if (vc > vm) { vm = vc; arg = ic; }
            if (vd > vm) { vm = vd; arg = id2; }
            vnew = vm + frow[j];
        }
        __syncthreads();
        if (wv == 0 && j < NTAG) {
            alpha[j] = anew;
        } else if (wv == 1 && j < NTAG) {
            valpha[j] = vnew;
            bp[t - 1][j] = (unsigned char)arg;
        }
        __syncthreads();
    }
    if (tid < NTAG) {
        red[tid]  = alpha[tid] + Tm[tid * NTAG + TSTOP];
        red2[tid] = valpha[tid] + Tm[tid * NTAG + TSTOP];
    }
    __syncthreads();
    // wave0: parallel gold transition+emission sum over t=1..len-1
    float gpart = 0.f;
    if (wv == 0) {
        const int* lab = blabel + b * TT;
        for (int t = 1 + j; t < len; t += 64)
            gpart += Tm[lab[t - 1] * NTAG + lab[t]] + fb[(size_t)t * NTAG + lab[t]];
#pragma unroll
        for (int m = 32; m; m >>= 1) gpart += __shfl_xor(gpart, m);
    }
    if (tid == 0) {
        float m1 = red[0];
        for (int i = 1; i < NTAG; i++) m1 = fmaxf(m1, red[i]);
        float ssum = 0.f;
        for (int i = 0; i < NTAG; i++) ssum += expf(red[i] - m1);
        float Zg = m1 + logf(ssum);
        const int* lab = blabel + b * TT;
        float goldv = Tm[TSTART * NTAG + lab[0]] + fb[lab[0]] + gpart
                    + Tm[lab[len - 1] * NTAG + TSTOP];
        lossb[b] = Zg - goldv;
    } else if (tid == 64) {
        int best = 0;
        float vm = red2[0];
        for (int i = 1; i < NTAG; i++)
            if (red2[i] > vm) { vm = red2[i]; best = i; }
        float* ot = outtags + (size_t)b * TT;
        int tag = best;
        ot[len - 1] = (float)tag;
        for (int t = len - 2; t >= 0; t--) {
            tag = bp[t][tag];
            ot[t] = (float)tag;
        }
        for (int t = len; t < TT; t++) ot[t] = 0.f;
    }
}

// ---- deterministic final loss reduction
__global__ void k_loss(const float* __restrict__ lossb, float* __restrict__ out) {
    if (threadIdx.x == 0 && blockIdx.x == 0) {
        float s = 0.f;
        for (int i = 0; i < BB; i++) s += lossb[i];
        out[0] = s;
    }
}

extern "C" void kernel_launch(void* const* d_in, const int* in_sizes, int n_in,
                              void* d_out, int out_size, void* d_ws, size_t ws_size,
                              hipStream_t stream) {
    const int* batch_word     = (const int*)d_in[0];
    const int* batch_features = (const int*)d_in[1];
    const int* batch_wordlen  = (const int*)d_in[2];
    const int* batch_char     = (const int*)d_in[3];
    const int* batch_recover  = (const int*)d_in[5];
    const int* batch_label    = (const int*)d_in[7];
    const float* char_emb = (const float*)d_in[8];
    const float* conv_w   = (const float*)d_in[9];
    const float* conv_b   = (const float*)d_in[10];
    const float* word_emb = (const float*)d_in[11];
    const float* feat_emb = (const float*)d_in[12];
    const float* w_ih_f   = (const float*)d_in[13];
    const float* w_hh_f   = (const float*)d_in[14];
    const float* b_f      = (const float*)d_in[15];
    const float* w_ih_b   = (const float*)d_in[16];
    const float* w_hh_b   = (const float*)d_in[17];
    const float* b_b      = (const float*)d_in[18];
    const float* proj_w   = (const float*)d_in[19];
    const float* proj_b   = (const float*)d_in[20];
    const float* trans    = (const float*)d_in[21];

    char* ws = (char*)d_ws;
    float* pooled   = (float*)(ws + OFF_POOL);
    _Float16* wh16f = (_Float16*)(ws + OFF_WH16F);
    _Float16* wh16b = (_Float16*)(ws + OFF_WH16B);
    _Float16* xh    = (_Float16*)(ws + OFF_XH);
    float* h_f    = (float*)(ws + OFF_HF);
    float* h_b    = (float*)(ws + OFF_HB);
    float* xs_f   = (float*)(ws + OFF_XSF);
    float* xs_b   = (float*)(ws + OFF_XSB);
    float* feats  = (float*)(ws + OFF_FEATS);
    _Float16* wh_f = (_Float16*)(ws + OFF_WPF);
    _Float16* wh_b = (_Float16*)(ws + OFF_WPB);
    float* lossb  = (float*)(ws + OFF_LOSSB);

    k_charcnn<<<(BB * TT) / 8, 256, 0, stream>>>(batch_char, char_emb, conv_w, conv_b, pooled);
    k_concat<<<(BB * TT) / 8, 128, 0, stream>>>(batch_word, batch_features, batch_recover,
                                                word_emb, feat_emb, pooled, xh);
    // pooled dead now -> wh16 conversions may overwrite that region.
    k_prep<<<5632, 256, 0, stream>>>(w_hh_f, w_hh_b, w_ih_f, w_ih_b,
                                     wh_f, wh_b, wh16f, wh16b);
    k_gemm16b<<<dim3(G4 / 64, (BB * TT) / 64), 256, 0, stream>>>(xh, wh16f, wh16b,
                                                                 b_f, b_b, xs_f, xs_b);
    k_lstm<<<128, 1024, 0, stream>>>(xs_f, xs_b, wh_f, wh_b, batch_wordlen, h_f, h_b);
    k_proj<<<(BB * TT) / 64, 256, 0, stream>>>(h_f, h_b, proj_w, proj_b, feats);
    k_crf<<<BB, 128, 0, stream>>>(feats, trans, batch_wordlen, batch_label,
                                  lossb, (float*)d_out + 1);
    k_loss<<<1, 64, 0, stream>>>(lossb, (float*)d_out);
}

// Round 13
// 1716.202 us; speedup vs baseline: 1.3965x; 1.1079x over previous
//
#include <hip/hip_runtime.h>
#include <hip/hip_bf16.h>
#include <math.h>

#define BB 64
#define TT 256
#define LCH 16
#define DC 50
#define CHN 100
#define DW 300
#define DF 20
#define HID 256
#define G4 1024
#define INDIM 420
#define KPAD 448
#define NTAG 52
#define TSTART 50
#define TSTOP 51

// ------------------- workspace layout (bytes) -------------------
static constexpr size_t OFF_POOL  = 0;                       // 6,553,600 (dead after concat)
static constexpr size_t OFF_WH16F = 0;                       // 917,504 f16 (after concat)
static constexpr size_t OFF_WH16B = 917504;                  // -> 1,835,008
static constexpr size_t OFF_XH    = 6553600;                 // 14,680,064 f16 -> 21,233,664
static constexpr size_t OFF_HF    = 0;                       // 16,777,216 (lstm output)
static constexpr size_t OFF_HB    = 16777216;                // -> 33,554,432
static constexpr size_t OFF_XSF   = 34078720;                // 67,108,864
static constexpr size_t OFF_XSB   = 101187584;               // -> 168,296,448
static constexpr size_t OFF_FEATS = 168296448;               // 3,407,872 -> 171,704,320
static constexpr size_t OFF_WPF   = 171704320;               // 512 KB fp16 packed W_hh fwd
static constexpr size_t OFF_WPB   = 172752896;               // 512 KB fp16 packed W_hh bwd
static constexpr size_t OFF_LOSSB = 173801472;               // 256

typedef _Float16 v2h __attribute__((ext_vector_type(2)));
typedef _Float16 f16x8 __attribute__((ext_vector_type(8)));
typedef float f32x4 __attribute__((ext_vector_type(4)));
union UH2 { unsigned u; v2h h; };
__device__ __forceinline__ float fdot2u(unsigned a, unsigned b, float c) {
    UH2 x, y; x.u = a; y.u = b;
    return __builtin_amdgcn_fdot2(x.h, y.h, c, false);
}
__device__ __forceinline__ float dot8(uint4 w, uint4 h, float acc) {
    acc = fdot2u(w.x, h.x, acc);
    acc = fdot2u(w.y, h.y, acc);
    acc = fdot2u(w.z, h.z, acc);
    acc = fdot2u(w.w, h.w, acc);
    return acc;
}
#define KEEPU4(v) asm volatile("" : "+v"((v).x), "+v"((v).y), "+v"((v).z), "+v"((v).w))

__device__ __forceinline__ float sigm(float x) { return 1.0f / (1.0f + expf(-x)); }

// ---- fused prep: pack W_hh (both dirs) + cvt w_ih (both dirs)
__device__ __forceinline__ void packh_one(const float* __restrict__ w,
                                          _Float16* __restrict__ wph, int e) {
    int r  = e & 7;
    int j  = (e >> 3) & 255;
    int k8 = (e >> 11) & 7;
    int g  = (e >> 14) & 3;
    int s  = (e >> 16) & 3;
    wph[e] = (_Float16)w[(g * 256 + j) * HID + (s * 64 + k8 * 8 + r)];
}
__device__ __forceinline__ void cvtw_one(const float* __restrict__ w,
                                         _Float16* __restrict__ wh, int e) {
    int row = e / KPAD, k = e % KPAD;
    wh[e] = (k < INDIM) ? (_Float16)w[row * INDIM + k] : (_Float16)0.f;
}
__global__ void k_prep(const float* __restrict__ whf, const float* __restrict__ whb,
                       const float* __restrict__ wihf, const float* __restrict__ wihb,
                       _Float16* __restrict__ wpf, _Float16* __restrict__ wpb,
                       _Float16* __restrict__ wh16f, _Float16* __restrict__ wh16b) {
    int e = blockIdx.x * 256 + threadIdx.x;          // grid 5632 blocks
    if (e < 262144)                packh_one(whf, wpf, e);
    else if (e < 524288)           packh_one(whb, wpb, e - 262144);
    else if (e < 524288 + 458752)  cvtw_one(wihf, wh16f, e - 524288);
    else if (e < 524288 + 917504)  cvtw_one(wihb, wh16b, e - 983040);
}

// ---- char CNN: 8 words/block (2 concurrent x 4 iterations); conv weights in LDS
__global__ __launch_bounds__(256) void k_charcnn(const int* __restrict__ bchar,
                                                 const float* __restrict__ cemb,
                                                 const float* __restrict__ cw,
                                                 const float* __restrict__ cb,
                                                 float* __restrict__ pooled) {
    __shared__ float cwsh[150][100];   // [d*3+q][c], 60 KB
    __shared__ float ET[2][DC][20];
    __shared__ int ids[2][LCH];
    int tid = threadIdx.x;
    int wbase = blockIdx.x * 8;
    for (int i = tid; i < 15000; i += 256) {
        int row = i / 100, c = i % 100;
        cwsh[row][c] = cw[c * 150 + row];
    }
    int half = tid >> 7, c = tid & 127;
    float bcv = (c < CHN) ? cb[c] : 0.f;
    for (int g = 0; g < 8; g += 2) {
        __syncthreads();
        if (tid < 32) ids[tid >> 4][tid & 15] = bchar[(wbase + g + (tid >> 4)) * LCH + (tid & 15)];
        __syncthreads();
        for (int s2 = tid; s2 < 2 * DC * 18; s2 += 256) {
            int w2 = s2 / 900, rem = s2 % 900;
            int d = rem / 18, l = rem % 18;
            float v = 0.f;
            if (l >= 1 && l <= 16) v = cemb[ids[w2][l - 1] * DC + d];
            ET[w2][d][l] = v;
        }
        __syncthreads();
        if (c < CHN) {
            float acc[16];
#pragma unroll
            for (int l = 0; l < 16; l++) acc[l] = 0.f;
            for (int d = 0; d < DC; d++) {
                float e[18];
                float4 t0 = *(const float4*)&ET[half][d][0];
                float4 t1 = *(const float4*)&ET[half][d][4];
                float4 t2 = *(const float4*)&ET[half][d][8];
                float4 t3 = *(const float4*)&ET[half][d][12];
                e[0]=t0.x; e[1]=t0.y; e[2]=t0.z; e[3]=t0.w;
                e[4]=t1.x; e[5]=t1.y; e[6]=t1.z; e[7]=t1.w;
                e[8]=t2.x; e[9]=t2.y; e[10]=t2.z; e[11]=t2.w;
                e[12]=t3.x; e[13]=t3.y; e[14]=t3.z; e[15]=t3.w;
                e[16]=ET[half][d][16]; e[17]=ET[half][d][17];
                float w0 = cwsh[d * 3 + 0][c];
                float w1 = cwsh[d * 3 + 1][c];
                float w2 = cwsh[d * 3 + 2][c];
#pragma unroll
                for (int l = 0; l < 16; l++)
                    acc[l] += w0 * e[l] + w1 * e[l + 1] + w2 * e[l + 2];
            }
            float m = acc[0];
#pragma unroll
            for (int l = 1; l < 16; l++) m = fmaxf(m, acc[l]);
            pooled[(wbase + g + half) * CHN + c] = m + bcv;
        }
    }
}

// ---- assemble xh[16384][448] f16; 8 words per block (2048 blocks)
__global__ __launch_bounds__(128) void k_concat(const int* __restrict__ word,
                                                const int* __restrict__ featsidx,
                                                const int* __restrict__ recover,
                                                const float* __restrict__ wemb,
                                                const float* __restrict__ femb,
                                                const float* __restrict__ pooled,
                                                _Float16* __restrict__ xh) {
    int tid = threadIdx.x;
    for (int wi = 0; wi < 8; wi++) {
        int w = blockIdx.x * 8 + wi;
        int b = w >> 8;
        int wid = word[w];
        _Float16* xr = xh + (size_t)w * KPAD;
        for (int c = tid; c < DW; c += 128) xr[c] = (_Float16)wemb[(size_t)wid * DW + c];
        int rc = recover[w];
        if (tid < CHN) xr[DW + tid] = (_Float16)pooled[rc * CHN + tid];
        if (tid < DF)  xr[DW + CHN + tid] = (_Float16)femb[featsidx[b] * DF + tid];
        if (tid >= 100 && tid < 100 + (KPAD - INDIM)) xr[INDIM + (tid - 100)] = (_Float16)0.f;
    }
}

// ---- fused f16 MFMA GEMM for BOTH directions, LDS-staged (coalesced).
// block 256 thr = 4 waves; tile 128(m) x 64(n) x {f,b}; BK=64.
// LDS rows padded to 72 f16 (144B, 16B-aligned) -> ds_read_b128 at the
// 128B/cyc floor. Per wave: 2 a-frags x 4 n-frags x 2 dirs = 16 mfma per
// k-step from 10 ds_reads. Accumulation k-order identical to the previous
// version -> bit-identical output.
__global__ __launch_bounds__(256, 4) void k_gemm16b(const _Float16* __restrict__ A,
                                                    const _Float16* __restrict__ Bf,
                                                    const _Float16* __restrict__ Bb,
                                                    const float* __restrict__ biasf,
                                                    const float* __restrict__ biasb,
                                                    float* __restrict__ Cf,
                                                    float* __restrict__ Cb) {
    __shared__ __align__(16) _Float16 Asl[128 * 72];
    __shared__ __align__(16) _Float16 Bfl[64 * 72];
    __shared__ __align__(16) _Float16 Bbl[64 * 72];
    int tid = threadIdx.x;
    int wv = tid >> 6, l = tid & 63;
    int lm = l & 15, lk = l >> 4;
    int n0 = blockIdx.x * 64, m0 = blockIdx.y * 128;
    f32x4 z = {0.f, 0.f, 0.f, 0.f};
    f32x4 af0 = z, af1 = z, af2 = z, af3 = z;   // a0 x bf[0..3]
    f32x4 ag0 = z, ag1 = z, ag2 = z, ag3 = z;   // a1 x bf[0..3]
    f32x4 ab0 = z, ab1 = z, ab2 = z, ab3 = z;   // a0 x bb[0..3]
    f32x4 ac0 = z, ac1 = z, ac2 = z, ac3 = z;   // a1 x bb[0..3]
    for (int k0 = 0; k0 < KPAD; k0 += 64) {
        __syncthreads();
#pragma unroll
        for (int q = 0; q < 4; q++) {           // A: 1024 chunks of 16B
            int ch = tid + q * 256;
            int r = ch >> 3, cc = ch & 7;
            ((uint4*)Asl)[r * 9 + cc] =
                *(const uint4*)&A[(size_t)(m0 + r) * KPAD + k0 + cc * 8];
        }
#pragma unroll
        for (int q = 0; q < 2; q++) {           // Bf/Bb: 512 chunks each
            int ch = tid + q * 256;
            int r = ch >> 3, cc = ch & 7;
            ((uint4*)Bfl)[r * 9 + cc] =
                *(const uint4*)&Bf[(size_t)(n0 + r) * KPAD + k0 + cc * 8];
            ((uint4*)Bbl)[r * 9 + cc] =
                *(const uint4*)&Bb[(size_t)(n0 + r) * KPAD + k0 + cc * 8];
        }
        __syncthreads();
#pragma unroll
        for (int kstep = 0; kstep < 2; kstep++) {
            int kk = kstep * 4 + lk;
            f16x8 a0 = ((const f16x8*)Asl)[(wv * 32 + lm) * 9 + kk];
            f16x8 a1 = ((const f16x8*)Asl)[(wv * 32 + 16 + lm) * 9 + kk];
            f16x8 b0 = ((const f16x8*)Bfl)[(0 * 16 + lm) * 9 + kk];
            f16x8 b1 = ((const f16x8*)Bfl)[(1 * 16 + lm) * 9 + kk];
            f16x8 b2 = ((const f16x8*)Bfl)[(2 * 16 + lm) * 9 + kk];
            f16x8 b3 = ((const f16x8*)Bfl)[(3 * 16 + lm) * 9 + kk];
            f16x8 c0 = ((const f16x8*)Bbl)[(0 * 16 + lm) * 9 + kk];
            f16x8 c1 = ((const f16x8*)Bbl)[(1 * 16 + lm) * 9 + kk];
            f16x8 c2 = ((const f16x8*)Bbl)[(2 * 16 + lm) * 9 + kk];
            f16x8 c3 = ((const f16x8*)Bbl)[(3 * 16 + lm) * 9 + kk];
            af0 = __builtin_amdgcn_mfma_f32_16x16x32_f16(a0, b0, af0, 0, 0, 0);
            af1 = __builtin_amdgcn_mfma_f32_16x16x32_f16(a0, b1, af1, 0, 0, 0);
            af2 = __builtin_amdgcn_mfma_f32_16x16x32_f16(a0, b2, af2, 0, 0, 0);
            af3 = __builtin_amdgcn_mfma_f32_16x16x32_f16(a0, b3, af3, 0, 0, 0);
            ag0 = __builtin_amdgcn_mfma_f32_16x16x32_f16(a1, b0, ag0, 0, 0, 0);
            ag1 = __builtin_amdgcn_mfma_f32_16x16x32_f16(a1, b1, ag1, 0, 0, 0);
            ag2 = __builtin_amdgcn_mfma_f32_16x16x32_f16(a1, b2, ag2, 0, 0, 0);
            ag3 = __builtin_amdgcn_mfma_f32_16x16x32_f16(a1, b3, ag3, 0, 0, 0);
            ab0 = __builtin_amdgcn_mfma_f32_16x16x32_f16(a0, c0, ab0, 0, 0, 0);
            ab1 = __builtin_amdgcn_mfma_f32_16x16x32_f16(a0, c1, ab1, 0, 0, 0);
            ab2 = __builtin_amdgcn_mfma_f32_16x16x32_f16(a0, c2, ab2, 0, 0, 0);
            ab3 = __builtin_amdgcn_mfma_f32_16x16x32_f16(a0, c3, ab3, 0, 0, 0);
            ac0 = __builtin_amdgcn_mfma_f32_16x16x32_f16(a1, c0, ac0, 0, 0, 0);
            ac1 = __builtin_amdgcn_mfma_f32_16x16x32_f16(a1, c1, ac1, 0, 0, 0);
            ac2 = __builtin_amdgcn_mfma_f32_16x16x32_f16(a1, c2, ac2, 0, 0, 0);
            ac3 = __builtin_amdgcn_mfma_f32_16x16x32_f16(a1, c3, ac3, 0, 0, 0);
        }
    }
    // C/D: col = lane&15, row = (lane>>4)*4 + r
    f32x4 fa[2][4] = {{af0, af1, af2, af3}, {ag0, ag1, ag2, ag3}};
    f32x4 ba[2][4] = {{ab0, ab1, ab2, ab3}, {ac0, ac1, ac2, ac3}};
#pragma unroll
    for (int mi = 0; mi < 2; mi++) {
        int orow = m0 + wv * 32 + mi * 16 + lk * 4;
#pragma unroll
        for (int jn = 0; jn < 4; jn++) {
            int col = n0 + jn * 16 + lm;
            float bvf = biasf[col], bvb = biasb[col];
#pragma unroll
            for (int r = 0; r < 4; r++) {
                Cf[(size_t)(orow + r) * G4 + col] = fa[mi][jn][r] + bvf;
                Cb[(size_t)(orow + r) * G4 + col] = ba[mi][jn][r] + bvb;
            }
        }
    }
}

// ---- masked BiLSTM (r8 structure, PLAIN loads): o-gate in 128 KB LDS;
// g-gate pinned in 32 VGPRs; i,f streamed 256 KB/step from L2.
__global__ __launch_bounds__(1024, 4) void k_lstm(const float* __restrict__ xs_f,
                                               const float* __restrict__ xs_b,
                                               const _Float16* __restrict__ wh_f,
                                               const _Float16* __restrict__ wh_b,
                                               const int* __restrict__ wlen,
                                               float* __restrict__ h_f,
                                               float* __restrict__ h_b) {
    int b = blockIdx.x & 63, d = blockIdx.x >> 6;
    const float* xs = d ? xs_b : xs_f;
    const uint4* wp4 = (const uint4*)(d ? wh_b : wh_f);
    float* ho = d ? h_b : h_f;
    int len = wlen[b];
    __shared__ uint4 olds4[8192];                 // o-gate weights, 128 KB
    __shared__ _Float16 __align__(16) hh[256];    // f16 h state
    __shared__ float part[4][4][256];             // [s][gate][unit], 16 KB
    int tid = threadIdx.x;
    int j = tid & 255, s = tid >> 8;
    const uint4* pi = wp4 + (size_t)((s * 4 + 0) * 8) * 256 + j;   // i (streamed)
    const uint4* pf = wp4 + (size_t)((s * 4 + 1) * 8) * 256 + j;   // f (streamed)
    uint4 wg[8];                                   // g-gate resident (32 VGPRs)
    {
        const uint4* pg = wp4 + (size_t)((s * 4 + 2) * 8) * 256 + j;
        const uint4* po = wp4 + (size_t)((s * 4 + 3) * 8) * 256 + j;
#pragma unroll
        for (int k8 = 0; k8 < 8; k8++) {
            wg[k8] = pg[k8 * 256];
            olds4[k8 * 1024 + tid] = po[k8 * 256];
        }
    }
#pragma unroll
    for (int k8 = 0; k8 < 8; k8++) KEEPU4(wg[k8]);
    if (tid < 128) ((unsigned*)hh)[tid] = 0u;
    float c = 0.f;
    const uint4* hsh4 = (const uint4*)hh;
    __syncthreads();
    for (int ss = 0; ss < len; ++ss) {
        int t = d ? (len - 1 - ss) : ss;
        float xv0, xv1, xv2, xv3;
        if (tid < 256) {
            const float* xr = xs + (size_t)(b * TT + t) * G4;
            xv0 = xr[tid];
            xv1 = xr[256 + tid];
            xv2 = xr[512 + tid];
            xv3 = xr[768 + tid];
        }
        asm volatile("" : "+v"(pi), "+v"(pf));
        float a0 = 0.f, a1 = 0.f, a2 = 0.f, a3 = 0.f;
#pragma unroll
        for (int k8 = 0; k8 < 8; k8++) {
            uint4 h4 = hsh4[s * 8 + k8];                       // broadcast
            uint4 wi = pi[k8 * 256];
            uint4 wf = pf[k8 * 256];
            uint4 wo = olds4[k8 * 1024 + tid];
            a0 = dot8(wi, h4, a0);
            a1 = dot8(wf, h4, a1);
            a2 = dot8(wg[k8], h4, a2);
            a3 = dot8(wo, h4, a3);
        }
        part[s][0][j] = a0;
        part[s][1][j] = a1;
        part[s][2][j] = a2;
        part[s][3][j] = a3;
        __syncthreads();
        if (tid < 256) {
            float s0 = part[0][0][tid] + part[1][0][tid] + part[2][0][tid] + part[3][0][tid] + xv0;
            float s1 = part[0][1][tid] + part[1][1][tid] + part[2][1][tid] + part[3][1][tid] + xv1;
            float s2 = part[0][2][tid] + part[1][2][tid] + part[2][2][tid] + part[3][2][tid] + xv2;
            float s3 = part[0][3][tid] + part[1][3][tid] + part[2][3][tid] + part[3][3][tid] + xv3;
            float ig = sigm(s0), fg = sigm(s1), zg = tanhf(s2), og = sigm(s3);
            c = fg * c + ig * zg;
            float h = og * tanhf(c);
            hh[tid] = (_Float16)h;
            ho[(size_t)(b * TT + t) * HID + tid] = h;
        }
        __syncthreads();
    }
}

// ---- projection: proj_w LDS-resident (stride-513 pad), 64 words per block
__global__ __launch_bounds__(256) void k_proj(const float* __restrict__ hf,
                                              const float* __restrict__ hb,
                                              const float* __restrict__ pw,
                                              const float* __restrict__ pb,
                                              float* __restrict__ feats) {
    __shared__ float pwsh[NTAG][513];
    __shared__ float hsh[512];
    __shared__ float part2[4][NTAG];
    int tid = threadIdx.x;
    int w0 = blockIdx.x * 64;
    for (int i = tid; i < NTAG * 512; i += 256) pwsh[i >> 9][i & 511] = pw[i];
    __syncthreads();
    int q = tid >> 6, t = tid & 63;
    for (int wi = 0; wi < 64; wi++) {
        int w = w0 + wi;
        hsh[tid]       = hf[(size_t)w * HID + tid];
        hsh[256 + tid] = hb[(size_t)w * HID + tid];
        __syncthreads();
        if (t < NTAG) {
            float ssum = 0.f;
            int k0 = q * 128;
            for (int k = 0; k < 128; k++) ssum += pwsh[t][k0 + k] * hsh[k0 + k];
            part2[q][t] = ssum;
        }
        __syncthreads();
        if (tid < NTAG)
            feats[(size_t)w * NTAG + tid] =
                part2[0][tid] + part2[1][tid] + part2[2][tid] + part2[3][tid] + pb[tid];
        __syncthreads();
    }
}

// ---- CRF: 2 waves; wave0 = forward logsumexp (+parallel gold), wave1 = viterbi.
__global__ __launch_bounds__(128) void k_crf(const float* __restrict__ feats,
                                             const float* __restrict__ trans,
                                             const int* __restrict__ wlen,
                                             const int* __restrict__ blabel,
                                             float* __restrict__ lossb,
                                             float* __restrict__ outtags) {
    __shared__ float Tm[NTAG * NTAG];
    __shared__ float alpha[NTAG], valpha[NTAG], frow[NTAG], red[NTAG], red2[NTAG];
    __shared__ unsigned char bp[TT - 1][NTAG];
    int b = blockIdx.x;
    int tid = threadIdx.x;
    int j = tid & 63, wv = tid >> 6;
    for (int s = tid; s < NTAG * NTAG; s += 128) Tm[s] = trans[s];
    __syncthreads();
    int len = wlen[b];
    const float* fb = feats + (size_t)b * TT * NTAG;
    if (tid < NTAG) {
        float a = fb[tid] + Tm[TSTART * NTAG + tid];
        alpha[tid] = a;
        valpha[tid] = a;
    }
    __syncthreads();
    for (int t = 1; t < len; t++) {
        if (tid < NTAG) frow[tid] = fb[(size_t)t * NTAG + tid];
        __syncthreads();
        float anew = 0.f, vnew = 0.f;
        int arg = 0;
        if (wv == 0 && j < NTAG) {
            float ma = -1e30f, mb = -1e30f, mc = -1e30f, md = -1e30f;
            for (int i = 0; i < 13; i++) {
                ma = fmaxf(ma, alpha[i]      + Tm[i * NTAG + j]);
                mb = fmaxf(mb, alpha[i + 13] + Tm[(i + 13) * NTAG + j]);
                mc = fmaxf(mc, alpha[i + 26] + Tm[(i + 26) * NTAG + j]);
                md = fmaxf(md, alpha[i + 39] + Tm[(i + 39) * NTAG + j]);
            }
            float m1 = fmaxf(fmaxf(ma, mb), fmaxf(mc, md));
            float sa = 0.f, sb = 0.f, sc = 0.f, sd = 0.f;
            for (int i = 0; i < 13; i++) {
                sa += expf(alpha[i]      + Tm[i * NTAG + j] - m1);
                sb += expf(alpha[i + 13] + Tm[(i + 13) * NTAG + j] - m1);
                sc += expf(alpha[i + 26] + Tm[(i + 26) * NTAG + j] - m1);
                sd += expf(alpha[i + 39] + Tm[(i + 39) * NTAG + j] - m1);
            }
            anew = m1 + logf((sa + sb) + (sc + sd)) + frow[j];
        } else if (wv == 1 && j < NTAG) {
            float va = -1e30f, vb = -1e30f, vc = -1e30f, vd = -1e30f;
            int ia = 0, ib = 13, ic = 26, id2 = 39;
            for (int i = 0; i < 13; i++) {
                float s0 = valpha[i]      + Tm[i * NTAG + j];        if (s0 > va) { va = s0; ia = i; }
                float s1 = valpha[i + 13] + Tm[(i + 13) * NTAG + j]; if (s1 > vb) { vb = s1; ib = i + 13; }
                float s2 = valpha[i + 26] + Tm[(i + 26) * NTAG + j]; if (s2 > vc) { vc = s2; ic = i + 26; }
                float s3 = valpha[i + 39] + Tm[(i + 39) * NTAG + j]; if (s3 > vd) { vd = s3; id2 = i + 39; }
            }
            float vm = va; arg = ia;
            if (vb > vm) { vm = vb; arg = ib; }
            if (vc > vm) { vm = vc; arg = ic; }
            if (vd > vm) { vm = vd; arg = id2; }
            vnew = vm + frow[j];
        }
        __syncthreads();
        if (wv == 0 && j < NTAG) {
            alpha[j] = anew;
        } else if (wv == 1 && j < NTAG) {
            valpha[j] = vnew;
            bp[t - 1][j] = (unsigned char)arg;
        }
        __syncthreads();
    }
    if (tid < NTAG) {
        red[tid]  = alpha[tid] + Tm[tid * NTAG + TSTOP];
        red2[tid] = valpha[tid] + Tm[tid * NTAG + TSTOP];
    }
    __syncthreads();
    // wave0: parallel gold transition+emission sum over t=1..len-1
    float gpart = 0.f;
    if (wv == 0) {
        const int* lab = blabel + b * TT;
        for (int t = 1 + j; t < len; t += 64)
            gpart += Tm[lab[t - 1] * NTAG + lab[t]] + fb[(size_t)t * NTAG + lab[t]];
#pragma unroll
        for (int m = 32; m; m >>= 1) gpart += __shfl_xor(gpart, m);
    }
    if (tid == 0) {
        float m1 = red[0];
        for (int i = 1; i < NTAG; i++) m1 = fmaxf(m1, red[i]);
        float ssum = 0.f;
        for (int i = 0; i < NTAG; i++) ssum += expf(red[i] - m1);
        float Zg = m1 + logf(ssum);
        const int* lab = blabel + b * TT;
        float goldv = Tm[TSTART * NTAG + lab[0]] + fb[lab[0]] + gpart
                    + Tm[lab[len - 1] * NTAG + TSTOP];
        lossb[b] = Zg - goldv;
    } else if (tid == 64) {
        int best = 0;
        float vm = red2[0];
        for (int i = 1; i < NTAG; i++)
            if (red2[i] > vm) { vm = red2[i]; best = i; }
        float* ot = outtags + (size_t)b * TT;
        int tag = best;
        ot[len - 1] = (float)tag;
        for (int t = len - 2; t >= 0; t--) {
            tag = bp[t][tag];
            ot[t] = (float)tag;
        }
        for (int t = len; t < TT; t++) ot[t] = 0.f;
    }
}

// ---- deterministic final loss reduction
__global__ void k_loss(const float* __restrict__ lossb, float* __restrict__ out) {
    if (threadIdx.x == 0 && blockIdx.x == 0) {
        float s = 0.f;
        for (int i = 0; i < BB; i++) s += lossb[i];
        out[0] = s;
    }
}

extern "C" void kernel_launch(void* const* d_in, const int* in_sizes, int n_in,
                              void* d_out, int out_size, void* d_ws, size_t ws_size,
                              hipStream_t stream) {
    const int* batch_word     = (const int*)d_in[0];
    const int* batch_features = (const int*)d_in[1];
    const int* batch_wordlen  = (const int*)d_in[2];
    const int* batch_char     = (const int*)d_in[3];
    const int* batch_recover  = (const int*)d_in[5];
    const int* batch_label    = (const int*)d_in[7];
    const float* char_emb = (const float*)d_in[8];
    const float* conv_w   = (const float*)d_in[9];
    const float* conv_b   = (const float*)d_in[10];
    const float* word_emb = (const float*)d_in[11];
    const float* feat_emb = (const float*)d_in[12];
    const float* w_ih_f   = (const float*)d_in[13];
    const float* w_hh_f   = (const float*)d_in[14];
    const float* b_f      = (const float*)d_in[15];
    const float* w_ih_b   = (const float*)d_in[16];
    const float* w_hh_b   = (const float*)d_in[17];
    const float* b_b      = (const float*)d_in[18];
    const float* proj_w   = (const float*)d_in[19];
    const float* proj_b   = (const float*)d_in[20];
    const float* trans    = (const float*)d_in[21];

    char* ws = (char*)d_ws;
    float* pooled   = (float*)(ws + OFF_POOL);
    _Float16* wh16f = (_Float16*)(ws + OFF_WH16F);
    _Float16* wh16b = (_Float16*)(ws + OFF_WH16B);
    _Float16* xh    = (_Float16*)(ws + OFF_XH);
    float* h_f    = (float*)(ws + OFF_HF);
    float* h_b    = (float*)(ws + OFF_HB);
    float* xs_f   = (float*)(ws + OFF_XSF);
    float* xs_b   = (float*)(ws + OFF_XSB);
    float* feats  = (float*)(ws + OFF_FEATS);
    _Float16* wh_f = (_Float16*)(ws + OFF_WPF);
    _Float16* wh_b = (_Float16*)(ws + OFF_WPB);
    float* lossb  = (float*)(ws + OFF_LOSSB);

    k_charcnn<<<(BB * TT) / 8, 256, 0, stream>>>(batch_char, char_emb, conv_w, conv_b, pooled);
    k_concat<<<(BB * TT) / 8, 128, 0, stream>>>(batch_word, batch_features, batch_recover,
                                                word_emb, feat_emb, pooled, xh);
    // pooled dead now -> wh16 conversions may overwrite that region.
    k_prep<<<5632, 256, 0, stream>>>(w_hh_f, w_hh_b, w_ih_f, w_ih_b,
                                     wh_f, wh_b, wh16f, wh16b);
    k_gemm16b<<<dim3(G4 / 64, (BB * TT) / 128), 256, 0, stream>>>(xh, wh16f, wh16b,
                                                                  b_f, b_b, xs_f, xs_b);
    k_lstm<<<128, 1024, 0, stream>>>(xs_f, xs_b, wh_f, wh_b, batch_wordlen, h_f, h_b);
    k_proj<<<(BB * TT) / 64, 256, 0, stream>>>(h_f, h_b, proj_w, proj_b, feats);
    k_crf<<<BB, 128, 0, stream>>>(feats, trans, batch_wordlen, batch_label,
                                  lossb, (float*)d_out + 1);
    k_loss<<<1, 64, 0, stream>>>(lossb, (float*)d_out);
}